// Round 3
// baseline (77.838 us; speedup 1.0000x reference)
//
#include <hip/hip_runtime.h>

#define N2 8192
#define NHALF 4096
#define DDIM 128
#define NCHUNK 8
#define CPC (N2/NCHUNK)   // 1024 cols per chunk
#define LN2F 0.69314718055994530942f
// SCALEF = sqrt(log2(e)/T) with T=0.5 -> sqrt(2.8853900817779268)
#define SCALEF 1.6986436f

typedef __attribute__((ext_vector_type(8))) short bf8_t;   // 8 bf16 = 4 VGPR (MFMA A/B frag)
typedef __attribute__((ext_vector_type(4))) float f4_t;    // MFMA C/D frag

__device__ __forceinline__ float fexp2(float x) {
#if __has_builtin(__builtin_amdgcn_exp2f)
  return __builtin_amdgcn_exp2f(x);
#else
  return exp2f(x);
#endif
}
__device__ __forceinline__ float flog2(float x) {
#if __has_builtin(__builtin_amdgcn_logf)
  return __builtin_amdgcn_logf(x);
#else
  return log2f(x);
#endif
}

__device__ __forceinline__ unsigned short f2bf(float f) {
  unsigned int x = __float_as_uint(f);
  x += 0x7fffu + ((x >> 16) & 1u);   // RNE (no NaN inputs here)
  return (unsigned short)(x >> 16);
}
__device__ __forceinline__ float bf2f(unsigned short h) {
  return __uint_as_float(((unsigned int)h) << 16);
}

// ---------------------------------------------------------------------------
// Kernel 1: normalize rows, scale by sqrt(log2e/T), store bf16 u[8192][128];
// also store dhat[i] = sum_k u_bf16[i][k]^2 (the diag logit, for correction).
// One wave per row. grid = 2048 x 256.
// ---------------------------------------------------------------------------
__global__ __launch_bounds__(256) void knorm(const float* __restrict__ zi,
                                             const float* __restrict__ zj,
                                             unsigned short* __restrict__ u,
                                             float* __restrict__ dhat) {
  const int lane = threadIdx.x & 63;
  const int row = blockIdx.x * 4 + (threadIdx.x >> 6);
  const float* src = (row < NHALF) ? (zi + (size_t)row * DDIM)
                                   : (zj + (size_t)(row - NHALF) * DDIM);
  float2 x = *(const float2*)(src + lane * 2);
  float ss = x.x * x.x + x.y * x.y;
#pragma unroll
  for (int m = 32; m; m >>= 1) ss += __shfl_xor(ss, m);
  float scale = SCALEF / fmaxf(sqrtf(ss), 1e-8f);  // eps clamp as in reference
  unsigned short b0 = f2bf(x.x * scale);
  unsigned short b1 = f2bf(x.y * scale);
  *(unsigned int*)(u + (size_t)row * DDIM + lane * 2) =
      (unsigned int)b0 | ((unsigned int)b1 << 16);
  float f0 = bf2f(b0), f1 = bf2f(b1);
  float dd = f0 * f0 + f1 * f1;
#pragma unroll
  for (int m = 32; m; m >>= 1) dd += __shfl_xor(dd, m);
  if (lane == 0) dhat[row] = dd;
}

// ---------------------------------------------------------------------------
// Kernel 2: fused sim GEMM + sum of exp2 per row (partial, per column chunk).
// Logits are bounded (|cos|<=1 -> |shat|<=2.89), so no max tracking needed.
// Block = 256 (4 waves); each wave owns 32 rows (2 A-sets of 16), iterates a
// 1024-col chunk in 16-col tiles: 4x global dwordx4 B-frag loads (L2-hot),
// 8 MFMA 16x16x32_bf16, 8 exp2+add. grid = 64 row-blocks x 8 chunks = 512 WGs.
// D-frag layout (verified): col = lane&15, row = (lane>>4)*4 + reg.
// ---------------------------------------------------------------------------
__global__ __launch_bounds__(256) void ksim(const unsigned short* __restrict__ u,
                                            float* __restrict__ Lp) {
  const int lane = threadIdx.x & 63;
  const int w = threadIdx.x >> 6;
  const int rb = blockIdx.x >> 3;       // / NCHUNK
  const int chunk = blockIdx.x & (NCHUNK - 1);
  const int lr = lane & 15, lq = lane >> 4;
  const int rowbase = rb * 128 + w * 32;

  bf8_t a[2][4];
#pragma unroll
  for (int s = 0; s < 2; s++)
#pragma unroll
    for (int kc = 0; kc < 4; kc++)
      a[s][kc] = *(const bf8_t*)(u + (size_t)(rowbase + s * 16 + lr) * DDIM +
                                 kc * 32 + lq * 8);

  f4_t L0 = {0.f, 0.f, 0.f, 0.f}, L1 = {0.f, 0.f, 0.f, 0.f};
  const unsigned short* ub = u + (size_t)(chunk * CPC + lr) * DDIM + lq * 8;

  for (int t = 0; t < CPC / 16; t++) {
    bf8_t b[4];
#pragma unroll
    for (int kc = 0; kc < 4; kc++)
      b[kc] = *(const bf8_t*)(ub + (size_t)t * 16 * DDIM + kc * 32);
    f4_t acc0 = {0.f, 0.f, 0.f, 0.f}, acc1 = {0.f, 0.f, 0.f, 0.f};
#pragma unroll
    for (int kc = 0; kc < 4; kc++) {
      acc0 = __builtin_amdgcn_mfma_f32_16x16x32_bf16(a[0][kc], b[kc], acc0, 0, 0, 0);
      acc1 = __builtin_amdgcn_mfma_f32_16x16x32_bf16(a[1][kc], b[kc], acc1, 0, 0, 0);
    }
#pragma unroll
    for (int r = 0; r < 4; r++) {
      L0[r] += fexp2(acc0[r]);
      L1[r] += fexp2(acc1[r]);
    }
  }

  // reduce across the 16 column-lanes (lanes sharing lq hold the same rows)
#pragma unroll
  for (int r = 0; r < 4; r++) {
    float v0 = L0[r], v1 = L1[r];
    v0 += __shfl_xor(v0, 1); v0 += __shfl_xor(v0, 2);
    v0 += __shfl_xor(v0, 4); v0 += __shfl_xor(v0, 8);
    v1 += __shfl_xor(v1, 1); v1 += __shfl_xor(v1, 2);
    v1 += __shfl_xor(v1, 4); v1 += __shfl_xor(v1, 8);
    if (lr == 0) {
      int rrow = rowbase + lq * 4 + r;
      Lp[(size_t)chunk * N2 + rrow] = v0;        // A-set 0 rows
      Lp[(size_t)chunk * N2 + rrow + 16] = v1;   // A-set 1 rows
    }
  }
}

// ---------------------------------------------------------------------------
// Kernel 3: per-row loss. L_i = sum_chunks - exp2(dhat_i) (removes diagonal);
// target logit from direct bf16 dot; loss_i = ln2*(log2(L_i) - that_target).
// One thread per row; block-reduced partial sums (deterministic).
// ---------------------------------------------------------------------------
__global__ __launch_bounds__(256) void krow(const unsigned short* __restrict__ u,
                                            const float* __restrict__ dhat,
                                            const float* __restrict__ Lp,
                                            float* __restrict__ bsum) {
  const int i = blockIdx.x * 256 + threadIdx.x;
  float L = 0.f;
#pragma unroll
  for (int c = 0; c < NCHUNK; c++) L += Lp[(size_t)c * N2 + i];
  L -= fexp2(dhat[i]);   // remove self-similarity term (== diag set to -inf)

  const int j = (i + NHALF) & (N2 - 1);  // positive-pair label
  const unsigned int* ui = (const unsigned int*)(u + (size_t)i * DDIM);
  const unsigned int* uj = (const unsigned int*)(u + (size_t)j * DDIM);
  float dot = 0.f;
#pragma unroll
  for (int k = 0; k < DDIM / 2; k++) {
    unsigned int av = ui[k], bv = uj[k];
    dot += __uint_as_float(av << 16) * __uint_as_float(bv << 16) +
           __uint_as_float(av & 0xffff0000u) * __uint_as_float(bv & 0xffff0000u);
  }
  float loss = LN2F * (flog2(L) - dot);

#pragma unroll
  for (int m = 32; m; m >>= 1) loss += __shfl_xor(loss, m);
  __shared__ float sred[4];
  if ((threadIdx.x & 63) == 0) sred[threadIdx.x >> 6] = loss;
  __syncthreads();
  if (threadIdx.x == 0) bsum[blockIdx.x] = sred[0] + sred[1] + sred[2] + sred[3];
}

// ---------------------------------------------------------------------------
// Kernel 4: final mean over the 32 block partials.
// ---------------------------------------------------------------------------
__global__ void kfinal(const float* __restrict__ bsum, float* __restrict__ out) {
  float v = (threadIdx.x < N2 / 256) ? bsum[threadIdx.x] : 0.f;
#pragma unroll
  for (int m = 32; m; m >>= 1) v += __shfl_xor(v, m);
  if (threadIdx.x == 0) out[0] = v * (1.0f / N2);
}

// ---------------------------------------------------------------------------
// ws layout: u bf16 [8192][128] (2 MB) | dhat f32[8192] (32 KB) |
//            Lp f32[8][8192] (256 KB) | bsum f32[32]
// total ~2.4 MB
// ---------------------------------------------------------------------------
extern "C" void kernel_launch(void* const* d_in, const int* in_sizes, int n_in,
                              void* d_out, int out_size, void* d_ws, size_t ws_size,
                              hipStream_t stream) {
  const float* zi = (const float*)d_in[0];
  const float* zj = (const float*)d_in[1];
  char* ws = (char*)d_ws;
  unsigned short* u = (unsigned short*)ws;
  float* dhat = (float*)(ws + (size_t)N2 * DDIM * 2);
  float* Lp = (float*)(ws + (size_t)N2 * DDIM * 2 + (size_t)N2 * 4);
  float* bsum = (float*)(ws + (size_t)N2 * DDIM * 2 + (size_t)N2 * 4 +
                         (size_t)NCHUNK * N2 * 4);
  float* out = (float*)d_out;

  hipLaunchKernelGGL(knorm, dim3(N2 / 4), dim3(256), 0, stream, zi, zj, u, dhat);
  hipLaunchKernelGGL(ksim, dim3((N2 / 128) * NCHUNK), dim3(256), 0, stream, u, Lp);
  hipLaunchKernelGGL(krow, dim3(N2 / 256), dim3(256), 0, stream, u, dhat, Lp, bsum);
  hipLaunchKernelGGL(kfinal, dim3(1), dim3(64), 0, stream, bsum, out);
}

// Round 4
// 70.162 us; speedup vs baseline: 1.1094x; 1.1094x over previous
//
#include <hip/hip_runtime.h>

#define N2 8192
#define NHALF 4096
#define DDIM 128
#define NCHUNK 32
#define CPC (N2/NCHUNK)   // 256 cols per chunk
#define RPB 256           // rows per workgroup (4 waves x 64)
#define LN2F 0.69314718055994530942f
// SCALEF = sqrt(log2(e)/T) with T=0.5 -> sqrt(2.8853900817779268)
#define SCALEF 1.6986436f

typedef __attribute__((ext_vector_type(8))) short bf8_t;   // 8 bf16 = 4 VGPR (MFMA A/B frag)
typedef __attribute__((ext_vector_type(4))) float f4_t;    // MFMA C/D frag

__device__ __forceinline__ float fexp2(float x) {
#if __has_builtin(__builtin_amdgcn_exp2f)
  return __builtin_amdgcn_exp2f(x);
#else
  return exp2f(x);
#endif
}
__device__ __forceinline__ float flog2(float x) {
#if __has_builtin(__builtin_amdgcn_logf)
  return __builtin_amdgcn_logf(x);
#else
  return log2f(x);
#endif
}

__device__ __forceinline__ unsigned short f2bf(float f) {
  unsigned int x = __float_as_uint(f);
  x += 0x7fffu + ((x >> 16) & 1u);   // RNE (no NaN inputs here)
  return (unsigned short)(x >> 16);
}
__device__ __forceinline__ float bf2f(unsigned short h) {
  return __uint_as_float(((unsigned int)h) << 16);
}

// ---------------------------------------------------------------------------
// Kernel 1: normalize rows, scale by sqrt(log2e/T), store bf16 u[8192][128];
// also store dhat[i] = sum_k u_bf16[i][k]^2 (the diag logit, for correction).
// One wave per row.
// ---------------------------------------------------------------------------
__global__ __launch_bounds__(256) void knorm(const float* __restrict__ zi,
                                             const float* __restrict__ zj,
                                             unsigned short* __restrict__ u,
                                             float* __restrict__ dhat) {
  const int lane = threadIdx.x & 63;
  const int row = blockIdx.x * 4 + (threadIdx.x >> 6);
  const float* src = (row < NHALF) ? (zi + (size_t)row * DDIM)
                                   : (zj + (size_t)(row - NHALF) * DDIM);
  float2 x = *(const float2*)(src + lane * 2);
  float ss = x.x * x.x + x.y * x.y;
#pragma unroll
  for (int m = 32; m; m >>= 1) ss += __shfl_xor(ss, m);
  float scale = SCALEF / fmaxf(sqrtf(ss), 1e-8f);  // eps clamp as in reference
  unsigned short b0 = f2bf(x.x * scale);
  unsigned short b1 = f2bf(x.y * scale);
  *(unsigned int*)(u + (size_t)row * DDIM + lane * 2) =
      (unsigned int)b0 | ((unsigned int)b1 << 16);
  float f0 = bf2f(b0), f1 = bf2f(b1);
  float dd = f0 * f0 + f1 * f1;
#pragma unroll
  for (int m = 32; m; m >>= 1) dd += __shfl_xor(dd, m);
  if (lane == 0) dhat[row] = dd;
}

// ---------------------------------------------------------------------------
// Kernel 2: fused sim GEMM + sum of exp2 per row (partial, per column chunk).
// Logits bounded (|shat|<=2.89) -> no max tracking. Block = 256 (4 waves);
// each wave owns 64 rows (4 A-sets of 16), iterates a 256-col chunk in 16-col
// tiles: 4 dwordx4 B-loads (L2-hot, double-buffered), 16 MFMA, 16 exp2+add.
// grid = 32 row-blocks x 32 chunks = 1024 WGs (4/CU, 16 waves/CU at <=128 VGPR).
// D-frag layout (validated r3): col = lane&15, row = (lane>>4)*4 + reg.
// ---------------------------------------------------------------------------
__global__ __launch_bounds__(256, 4) void ksim(const unsigned short* __restrict__ u,
                                               float* __restrict__ Lp) {
  const int lane = threadIdx.x & 63;
  const int w = threadIdx.x >> 6;
  const int rb = blockIdx.x >> 5;        // / NCHUNK
  const int chunk = blockIdx.x & (NCHUNK - 1);
  const int lr = lane & 15, lq = lane >> 4;
  const int rowbase = rb * RPB + w * 64;

  bf8_t a[4][4];
#pragma unroll
  for (int s = 0; s < 4; s++)
#pragma unroll
    for (int kc = 0; kc < 4; kc++)
      a[s][kc] = *(const bf8_t*)(u + (size_t)(rowbase + s * 16 + lr) * DDIM +
                                 kc * 32 + lq * 8);

  f4_t L[4];
#pragma unroll
  for (int s = 0; s < 4; s++) L[s] = (f4_t){0.f, 0.f, 0.f, 0.f};

  const unsigned short* ub = u + (size_t)(chunk * CPC + lr) * DDIM + lq * 8;

  auto loadB = [&](int t, bf8_t* b) {
#pragma unroll
    for (int kc = 0; kc < 4; kc++)
      b[kc] = *(const bf8_t*)(ub + (size_t)t * 16 * DDIM + kc * 32);
  };
  auto comp = [&](bf8_t* b) {
    f4_t acc[4];
#pragma unroll
    for (int s = 0; s < 4; s++) acc[s] = (f4_t){0.f, 0.f, 0.f, 0.f};
#pragma unroll
    for (int kc = 0; kc < 4; kc++)
#pragma unroll
      for (int s = 0; s < 4; s++)
        acc[s] = __builtin_amdgcn_mfma_f32_16x16x32_bf16(a[s][kc], b[kc], acc[s], 0, 0, 0);
#pragma unroll
    for (int s = 0; s < 4; s++)
#pragma unroll
      for (int r = 0; r < 4; r++) L[s][r] += fexp2(acc[s][r]);
  };

  bf8_t b0[4], b1[4];
  loadB(0, b0);
  for (int t = 0; t < CPC / 16 - 2; t += 2) {
    loadB(t + 1, b1);
    comp(b0);
    loadB(t + 2, b0);
    comp(b1);
  }
  loadB(CPC / 16 - 1, b1);
  comp(b0);
  comp(b1);

  // reduce across the 16 column-lanes (lanes sharing lq hold the same rows)
#pragma unroll
  for (int s = 0; s < 4; s++)
#pragma unroll
    for (int r = 0; r < 4; r++) {
      float v = L[s][r];
      v += __shfl_xor(v, 1); v += __shfl_xor(v, 2);
      v += __shfl_xor(v, 4); v += __shfl_xor(v, 8);
      if (lr == 0)
        Lp[(size_t)chunk * N2 + rowbase + s * 16 + lq * 4 + r] = v;
    }
}

// ---------------------------------------------------------------------------
// Kernel 3: per-row loss. L_i = sum_chunks - exp2(dhat_i) (removes diagonal);
// target logit from direct bf16 dot; loss_i = ln2*(log2(L_i) - target).
// One thread per row; block-reduced partial sums (deterministic).
// ---------------------------------------------------------------------------
__global__ __launch_bounds__(256) void krow(const unsigned short* __restrict__ u,
                                            const float* __restrict__ dhat,
                                            const float* __restrict__ Lp,
                                            float* __restrict__ bsum) {
  const int i = blockIdx.x * 256 + threadIdx.x;
  float L = 0.f;
#pragma unroll
  for (int c = 0; c < NCHUNK; c++) L += Lp[(size_t)c * N2 + i];
  L -= fexp2(dhat[i]);   // remove self-similarity term (== diag set to -inf)

  const int j = (i + NHALF) & (N2 - 1);  // positive-pair label
  const unsigned int* ui = (const unsigned int*)(u + (size_t)i * DDIM);
  const unsigned int* uj = (const unsigned int*)(u + (size_t)j * DDIM);
  float dot = 0.f;
#pragma unroll
  for (int k = 0; k < DDIM / 2; k++) {
    unsigned int av = ui[k], bv = uj[k];
    dot += __uint_as_float(av << 16) * __uint_as_float(bv << 16) +
           __uint_as_float(av & 0xffff0000u) * __uint_as_float(bv & 0xffff0000u);
  }
  float loss = LN2F * (flog2(L) - dot);

#pragma unroll
  for (int m = 32; m; m >>= 1) loss += __shfl_xor(loss, m);
  __shared__ float sred[4];
  if ((threadIdx.x & 63) == 0) sred[threadIdx.x >> 6] = loss;
  __syncthreads();
  if (threadIdx.x == 0) bsum[blockIdx.x] = sred[0] + sred[1] + sred[2] + sred[3];
}

// ---------------------------------------------------------------------------
// Kernel 4: final mean over the 32 block partials.
// ---------------------------------------------------------------------------
__global__ void kfinal(const float* __restrict__ bsum, float* __restrict__ out) {
  float v = (threadIdx.x < N2 / 256) ? bsum[threadIdx.x] : 0.f;
#pragma unroll
  for (int m = 32; m; m >>= 1) v += __shfl_xor(v, m);
  if (threadIdx.x == 0) out[0] = v * (1.0f / N2);
}

// ---------------------------------------------------------------------------
// ws layout: u bf16 [8192][128] (2 MB) | dhat f32[8192] (32 KB) |
//            Lp f32[32][8192] (1 MB) | bsum f32[32]   -> ~3.03 MB total
// ---------------------------------------------------------------------------
extern "C" void kernel_launch(void* const* d_in, const int* in_sizes, int n_in,
                              void* d_out, int out_size, void* d_ws, size_t ws_size,
                              hipStream_t stream) {
  const float* zi = (const float*)d_in[0];
  const float* zj = (const float*)d_in[1];
  char* ws = (char*)d_ws;
  unsigned short* u = (unsigned short*)ws;
  float* dhat = (float*)(ws + (size_t)N2 * DDIM * 2);
  float* Lp = (float*)(ws + (size_t)N2 * DDIM * 2 + (size_t)N2 * 4);
  float* bsum = (float*)(ws + (size_t)N2 * DDIM * 2 + (size_t)N2 * 4 +
                         (size_t)NCHUNK * N2 * 4);
  float* out = (float*)d_out;

  hipLaunchKernelGGL(knorm, dim3(N2 / 4), dim3(256), 0, stream, zi, zj, u, dhat);
  hipLaunchKernelGGL(ksim, dim3((N2 / RPB) * NCHUNK), dim3(256), 0, stream, u, Lp);
  hipLaunchKernelGGL(krow, dim3(N2 / 256), dim3(256), 0, stream, u, dhat, Lp, bsum);
  hipLaunchKernelGGL(kfinal, dim3(1), dim3(64), 0, stream, bsum, out);
}